// Round 20
// baseline (581.929 us; speedup 1.0000x reference)
//
#include <hip/hip_runtime.h>
#include <hip/hip_bf16.h>
#include <math.h>

// Problem constants (fixed by setup_inputs)
#define BB 16
#define CC 192
#define TS 2048
#define TT 512
#define KK 384   // 2*CC

// d_out float offsets
#define OFF_PATH 0
#define OFF_DUR  (16777216)
#define OFF_LOGW (OFF_DUR + 8192)
#define OFF_MEXP (OFF_LOGW + 8192)
#define OFF_LEXP (OFF_MEXP + 6291456)
#define OFF_TMASK (OFF_LEXP + 6291456)
#define OFF_SMASK (OFF_TMASK + 8192)

#define NEGCF (-1e9f)

// ---------------------------------------------------------------------------
// prep (parallelized: 256 blocks = full chip).
__global__ __launch_bounds__(512) void vits_prep(
    const float* __restrict__ m_p, const float* __restrict__ logs_p,
    const int* __restrict__ spec_len, const int* __restrict__ text_len,
    float* __restrict__ Bmat, float* __restrict__ avec,
    float* __restrict__ tmask, float* __restrict__ smask)
{
    const int uc = blockIdx.x;          // 0..15 (u-chunk of 32)
    const int b  = blockIdx.y;
    const int tid = threadIdx.x;
    const int ul = tid & 31;
    const int cg = tid >> 5;            // 0..15
    const int u = uc*32 + ul;
    const float C0 = -0.91893853320467274178f; // -0.5*log(2*pi)
    float a_acc = 0.f;
    for (int c = cg; c < CC; c += 16) {
        float lg = logs_p[((size_t)b*CC + c)*TT + u];
        float mm = m_p[((size_t)b*CC + c)*TT + u];
        float s  = expf(-2.f*lg);
        float ms = mm * s;
        Bmat[((size_t)b*KK + 2*c    )*TT + u] = ms;
        Bmat[((size_t)b*KK + 2*c + 1)*TT + u] = s;
        a_acc += C0 - lg - 0.5f*mm*ms;
    }
    __shared__ float red[16][33];
    red[cg][ul] = a_acc;
    __syncthreads();
    #pragma unroll
    for (int s = 8; s > 0; s >>= 1) {
        if (cg < s) red[cg][ul] += red[cg + s][ul];
        __syncthreads();
    }
    if (cg == 0) {
        avec[b*TT + u] = red[0][ul];
        tmask[b*TT + u] = (u < text_len[b]) ? 1.f : 0.f;
    }
    if (tid < 128) {
        int t = uc*128 + tid;
        smask[b*TS + t] = (t < spec_len[b]) ? 1.f : 0.f;
    }
}

// ---------------------------------------------------------------------------
// gemm: nc[b][t][u] = avec[b][u] + sum_k X[k][t] * Bmat[k][u]
// X[2c][t] = z[b][c][t], X[2c+1][t] = -0.5*z^2.
// 128x256 tile, 512 threads, 8x8 microtile. Near the f32 FLOP floor (~82us).
// Per-output k-accumulation order is ascending k with one FMA each —
// bit-identical nc across rounds.
__global__ __launch_bounds__(512, 2) void vits_gemm(
    const float* __restrict__ z, const float* __restrict__ Bmat,
    const float* __restrict__ avec, float* __restrict__ out)
{
    const int b  = blockIdx.z;
    const int t0 = blockIdx.y * 128;
    const int u0 = blockIdx.x * 256;
    __shared__ float As[8][128];
    __shared__ float Bs[8][256];
    const int tid = threadIdx.x;
    const int tx = tid & 31, ty = tid >> 5;      // tx: u-group, ty: t-group
    float acc[8][8] = {};
    const float* zb = z    + (size_t)b * CC * TS;
    const float* Bb = Bmat + (size_t)b * KK * TT;

    const int c_l = tid >> 6;           // z channel (0..3 used, tid<256)
    const int t_l = (tid & 63) * 2;     // 0..126
    const int k_b = tid >> 6;           // 0..7 (B: 8 rows/panel)
    const int u_l = (tid & 63) * 4;     // 0..252

    float2 zr = make_float2(0.f, 0.f);
    if (tid < 256) zr = *(const float2*)(zb + (size_t)c_l*TS + t0 + t_l);
    float4 br = *(const float4*)(Bb + (size_t)k_b*TT + u0 + u_l);

    for (int kc = 0; kc < KK/8; ++kc) {
        if (tid < 256) {
            *(float2*)&As[2*c_l  ][t_l] = make_float2(zr.x, zr.y);
            *(float2*)&As[2*c_l+1][t_l] = make_float2(-0.5f*zr.x*zr.x, -0.5f*zr.y*zr.y);
        }
        *(float4*)&Bs[k_b][u_l] = br;
        __syncthreads();
        if (kc + 1 < KK/8) {            // prefetch next panel (overlaps compute)
            if (tid < 256)
                zr = *(const float2*)(zb + (size_t)((kc+1)*4 + c_l)*TS + t0 + t_l);
            br = *(const float4*)(Bb + (size_t)((kc+1)*8 + k_b)*TT + u0 + u_l);
        }
        #pragma unroll
        for (int k = 0; k < 8; ++k) {
            float4 a0 = *(const float4*)&As[k][ty*4];
            float4 a1 = *(const float4*)&As[k][ty*4 + 64];
            float4 b0 = *(const float4*)&Bs[k][tx*4];
            float4 b1 = *(const float4*)&Bs[k][tx*4 + 128];
            float aa[8] = {a0.x,a0.y,a0.z,a0.w,a1.x,a1.y,a1.z,a1.w};
            float bb[8] = {b0.x,b0.y,b0.z,b0.w,b1.x,b1.y,b1.z,b1.w};
            #pragma unroll
            for (int i = 0; i < 8; ++i)
                #pragma unroll
                for (int j = 0; j < 8; ++j)
                    acc[i][j] += aa[i]*bb[j];
        }
        __syncthreads();
    }

    float4 ab0 = *(const float4*)(avec + b*TT + u0 + tx*4);
    float4 ab1 = *(const float4*)(avec + b*TT + u0 + tx*4 + 128);
    float ab[8] = {ab0.x,ab0.y,ab0.z,ab0.w,ab1.x,ab1.y,ab1.z,ab1.w};
    #pragma unroll
    for (int i = 0; i < 8; ++i) {
        int tt = t0 + ((i < 4) ? (ty*4 + i) : (64 + ty*4 + (i-4)));
        float* orow = out + (size_t)((size_t)b*TS + tt)*TT + u0;
        float4 o0, o1;
        o0.x = acc[i][0] + ab[0]; o0.y = acc[i][1] + ab[1];
        o0.z = acc[i][2] + ab[2]; o0.w = acc[i][3] + ab[3];
        o1.x = acc[i][4] + ab[4]; o1.y = acc[i][5] + ab[5];
        o1.z = acc[i][6] + ab[6]; o1.w = acc[i][7] + ab[7];
        *(float4*)(orow + tx*4)       = o0;
        *(float4*)(orow + tx*4 + 128) = o1;
    }
}

// ---------------------------------------------------------------------------
// DPP full-wave rotate-by-1: lane n <- lane (n-1)&63 (wave_ror:1 = 0x13C).
__device__ __forceinline__ float dpp_ror1_f32(float v) {
    union { float f; int i; } u, r;
    u.f = v;
    r.i = __builtin_amdgcn_update_dpp(0, u.i, 0x13C, 0xF, 0xF, false);
    return r.f;
}

// ---------------------------------------------------------------------------
// dp: forward Viterbi (f32), SYSTOLIC wave-skewed tiling, prefetch ring 64
// (vmcnt-cap depth; the dp is outstanding-miss x LLC-latency bound at
// 32 unique lines/step/CU). 8 waves x 64 auth columns, no ghost columns.
// Wave w runs chunk c (32 steps) only after wave w-1 completed chunk c
// (LDS prog[] + s_sleep spin; no barriers in the loop). Boundary
// q[t-1][64w-1] flows via a 256-slot LDS ring; 6-chunk flow gate guards
// aliasing; waits acyclic.
// dirs bit-packed per col along t (32-t windows), bank-swizzled.
#define DIRS(j,w) dirs[((j)<<6) | ((w) ^ ((j) & 31))]
#define RING 64

__global__ __launch_bounds__(512, 1) void vits_dp(
    const float* __restrict__ nc,
    const int* __restrict__ spec_len, const int* __restrict__ text_len,
    float* __restrict__ dur, float* __restrict__ logw, int* __restrict__ jt)
{
    __shared__ unsigned int dirs[TT*(TS/32)];   // 128 KB (swizzled)
    __shared__ float bq[8][256];                // 8 KB boundary rings
    __shared__ int prog[8];                     // completed chunks per wave
    __shared__ int Tr[TT + 1];                  // 2 KB

    const int tid  = threadIdx.x;
    const int lane = tid & 63;
    const int wid  = tid >> 6;                  // 0..7
    const int b = blockIdx.x;
    const int SL = spec_len[b], TL = text_len[b];
    const int col = (wid << 6) + lane;          // every lane is authoritative
    const bool l0  = (lane == 0);
    const bool l63 = (lane == 63);

    float q = (col == 0) ? 0.0f : NEGCF;
    unsigned int bits = 0;

    const float* ncb = nc + (size_t)b*TS*TT + col;
    float pf[RING];
    #pragma unroll
    for (int i = 0; i < RING; ++i) pf[i] = ncb[(size_t)i*TT];
    const float* pcur = ncb + (size_t)RING*TT;  // rows past SL read junk inside d_out; never consumed

    for (int i = tid; i < 8*256; i += 512) ((float*)bq)[i] = NEGCF;
    if (tid < 8) prog[tid] = 0;
    __syncthreads();

    volatile int* vprog = (volatile int*)prog;
    const int nch = SL >> 5;

    for (int c = 0; c < nch; ++c) {
        if (wid > 0) { while (vprog[wid-1] < c+1) __builtin_amdgcn_s_sleep(1); }
        if (wid < 7 && c > 6) { while (vprog[wid+1] < c-6) __builtin_amdgcn_s_sleep(1); }
        asm volatile("" ::: "memory");

        // boundary values for this chunk: slots (32c-4 .. 32c+31) & 255
        float4 R[9];
        R[0] = *(const float4*)&bq[wid][(c*32 + 252) & 255];
        #pragma unroll
        for (int g = 1; g < 9; ++g)
            R[g] = *(const float4*)&bq[wid][(c*32 + (g-1)*4) & 255];

        float4 wbuf;
        #pragma unroll
        for (int s = 0; s < 32; ++s) {
            float f = pf[(c*32 + s) & (RING-1)];
            pf[(c*32 + s) & (RING-1)] = *pcur;   // prefetch row t+RING
            pcur += TT;
            // boundary for step t=32c+s lives at slot 32c-1+s -> R[(s+3)/4][(s+3)%4]
            float B = ((const float*)&R[(s+3) >> 2])[(s+3) & 3];
            float qr = dpp_ror1_f32(q);
            float qprev = l0 ? B : qr;           // q[t-1][col-1]
            bool d = (qprev >= q);               // ref: q_shift >= q
            bits = (bits << 1) | (unsigned)d;
            q = f + fmaxf(qprev, q);
            ((float*)&wbuf)[s & 3] = q;          // static index (unrolled)
            if ((s & 3) == 3) {
                if (l63 && wid < 7)
                    *(float4*)&bq[wid+1][(c*32 + s - 3) & 255] = wbuf;
            }
        }
        DIRS(col, c) = bits;
        bits = 0;
        asm volatile("s_waitcnt lgkmcnt(0)" ::: "memory");
        if (l0) vprog[wid] = c + 1;
    }

    // tail (SL & 31 steps): fully serialized across waves (tiny)
    const int rem = SL & 31;
    if (rem) {
        if (wid > 0) { while (vprog[wid-1] < nch+1) __builtin_amdgcn_s_sleep(1); }
        asm volatile("" ::: "memory");
        for (int t = nch*32; t < SL; ++t) {
            float f = ncb[(size_t)t*TT];
            float B = *(volatile float*)&bq[wid][(t-1) & 255];
            float qr = dpp_ror1_f32(q);
            float qprev = l0 ? B : qr;
            bool d = (qprev >= q);
            bits = (bits << 1) | (unsigned)d;
            q = f + fmaxf(qprev, q);
            if (l63 && wid < 7) *(volatile float*)&bq[wid+1][t & 255] = q;
            asm volatile("s_waitcnt lgkmcnt(0)" ::: "memory");
        }
        DIRS(col, SL >> 5) = bits << (32 - rem);
        asm volatile("s_waitcnt lgkmcnt(0)" ::: "memory");
        if (l0) vprog[wid] = nch + 1;
    }
    __syncthreads();

    for (int i = tid; i <= TT; i += 512) Tr[i] = 0;
    __syncthreads();

    if (tid == 0) {
        Tr[TL] = SL;
        int j = TL - 1, tc = SL - 1;
        // Tr[j] = first frame aligned to text index j (transition time)
        while (j > 0 && tc >= 0) {
            int w = tc >> 5;
            int bcur = 31 - (tc & 31);
            unsigned int W = DIRS(j, w) & (0xFFFFFFFFu << bcur);
            if (W) {
                int bp = __ffs(W) - 1;          // lowest set bit >= bcur
                int tp = (w << 5) + 31 - bp;    // = largest t' <= tc with d=1
                Tr[j] = tp;
                --j;
                tc = tp - 1;
            } else {
                if (w == 0) break;
                tc = (w << 5) - 1;
            }
        }
    }
    __syncthreads();

    for (int u = tid; u < TT; u += 512) {
        float dv = (u < TL) ? (float)(Tr[u+1] - Tr[u]) : 0.0f;
        dur[b*TT + u] = dv;
        logw[b*TT + u] = (u < TL) ? logf(dv + 1e-6f) : 0.0f;
    }
    // jt: range-fill [Tr[u], Tr[u+1]) -> u
    for (int u = 0; u < TL; ++u) {
        int t1 = Tr[u+1];
        for (int t = Tr[u] + tid; t < t1; t += 512) jt[b*TS + t] = u;
    }
    for (int t = SL + tid; t < TS; t += 512) jt[b*TS + t] = -1;
}

// ---------------------------------------------------------------------------
// fused output pass: blocks [0, PB) write path (one-hot rows), blocks
// [PB, PB+MB) write mexp/lexp gathers. One launch, shared BW.
#define PB 1024
#define MB 2048
__global__ void vits_out(const int* __restrict__ jt,
    const float* __restrict__ m_p, const float* __restrict__ logs_p,
    float4* __restrict__ path, float4* __restrict__ mexp, float4* __restrict__ lexp)
{
    if (blockIdx.x < PB) {
        int idx = blockIdx.x*blockDim.x + threadIdx.x;
        const int total = BB*TS*(TT/4);
        for (; idx < total; idx += PB*blockDim.x) {
            int u4 = idx & (TT/4 - 1);
            int bt = idx >> 7;
            int j = jt[bt];
            float4 v = make_float4(0.f,0.f,0.f,0.f);
            int r = j - (u4 << 2);
            if (r >= 0 && r < 4) ((float*)&v)[r] = 1.f;
            path[idx] = v;
        }
    } else {
        int idx = (blockIdx.x - PB)*blockDim.x + threadIdx.x;
        const int total = BB*CC*(TS/4);
        for (; idx < total; idx += MB*blockDim.x) {
            int t4 = idx & (TS/4 - 1);
            int bc = idx >> 9;
            int b = bc / CC;
            int4 jv = *(const int4*)(jt + b*TS + (t4 << 2));
            const float* mrow = m_p    + (size_t)bc*TT;
            const float* lrow = logs_p + (size_t)bc*TT;
            float4 mv, lv;
            mv.x = (jv.x >= 0) ? mrow[jv.x] : 0.f;  lv.x = (jv.x >= 0) ? lrow[jv.x] : 0.f;
            mv.y = (jv.y >= 0) ? mrow[jv.y] : 0.f;  lv.y = (jv.y >= 0) ? lrow[jv.y] : 0.f;
            mv.z = (jv.z >= 0) ? mrow[jv.z] : 0.f;  lv.z = (jv.z >= 0) ? lrow[jv.z] : 0.f;
            mv.w = (jv.w >= 0) ? mrow[jv.w] : 0.f;  lv.w = (jv.w >= 0) ? lrow[jv.w] : 0.f;
            mexp[idx] = mv;
            lexp[idx] = lv;
        }
    }
}

// ---------------------------------------------------------------------------
extern "C" void kernel_launch(void* const* d_in, const int* in_sizes, int n_in,
                              void* d_out, int out_size, void* d_ws, size_t ws_size,
                              hipStream_t stream) {
    const float* z_p      = (const float*)d_in[0];
    const float* m_p      = (const float*)d_in[1];
    const float* logs_p   = (const float*)d_in[2];
    const int*   spec_len = (const int*)d_in[3];
    const int*   text_len = (const int*)d_in[4];
    float* out = (float*)d_out;

    float* Bmat = (float*)d_ws;                  // [B][384][512] f32 = 12.6 MB
    float* avec = Bmat + (size_t)BB*KK*TT;       // [B][512]
    int*   jt   = (int*)(avec + BB*TT);          // [B][2048]

    float* path  = out + OFF_PATH;   // doubles as neg_cent staging
    float* dur   = out + OFF_DUR;
    float* logw  = out + OFF_LOGW;
    float* mexp  = out + OFF_MEXP;
    float* lexp  = out + OFF_LEXP;
    float* tmask = out + OFF_TMASK;
    float* smask = out + OFF_SMASK;

    vits_prep<<<dim3(16, BB), 512, 0, stream>>>(m_p, logs_p, spec_len, text_len,
                                                Bmat, avec, tmask, smask);
    vits_gemm<<<dim3(TT/256, TS/128, BB), 512, 0, stream>>>(z_p, Bmat, avec, path);
    vits_dp<<<BB, 512, 0, stream>>>(path, spec_len, text_len, dur, logw, jt);
    vits_out<<<PB + MB, 256, 0, stream>>>(jt, m_p, logs_p,
                                          (float4*)path, (float4*)mexp, (float4*)lexp);
}

// Round 21
// 398.966 us; speedup vs baseline: 1.4586x; 1.4586x over previous
//
#include <hip/hip_runtime.h>
#include <hip/hip_bf16.h>
#include <math.h>

// Problem constants (fixed by setup_inputs)
#define BB 16
#define CC 192
#define TS 2048
#define TT 512
#define KK 384   // 2*CC

// d_out float offsets
#define OFF_PATH 0
#define OFF_DUR  (16777216)
#define OFF_LOGW (OFF_DUR + 8192)
#define OFF_MEXP (OFF_LOGW + 8192)
#define OFF_LEXP (OFF_MEXP + 6291456)
#define OFF_TMASK (OFF_LEXP + 6291456)
#define OFF_SMASK (OFF_TMASK + 8192)

#define NEGCF (-1e9f)

// ---------------------------------------------------------------------------
// prep (parallelized: 256 blocks = full chip).
__global__ __launch_bounds__(512) void vits_prep(
    const float* __restrict__ m_p, const float* __restrict__ logs_p,
    const int* __restrict__ spec_len, const int* __restrict__ text_len,
    float* __restrict__ Bmat, float* __restrict__ avec,
    float* __restrict__ tmask, float* __restrict__ smask)
{
    const int uc = blockIdx.x;          // 0..15 (u-chunk of 32)
    const int b  = blockIdx.y;
    const int tid = threadIdx.x;
    const int ul = tid & 31;
    const int cg = tid >> 5;            // 0..15
    const int u = uc*32 + ul;
    const float C0 = -0.91893853320467274178f; // -0.5*log(2*pi)
    float a_acc = 0.f;
    for (int c = cg; c < CC; c += 16) {
        float lg = logs_p[((size_t)b*CC + c)*TT + u];
        float mm = m_p[((size_t)b*CC + c)*TT + u];
        float s  = expf(-2.f*lg);
        float ms = mm * s;
        Bmat[((size_t)b*KK + 2*c    )*TT + u] = ms;
        Bmat[((size_t)b*KK + 2*c + 1)*TT + u] = s;
        a_acc += C0 - lg - 0.5f*mm*ms;
    }
    __shared__ float red[16][33];
    red[cg][ul] = a_acc;
    __syncthreads();
    #pragma unroll
    for (int s = 8; s > 0; s >>= 1) {
        if (cg < s) red[cg][ul] += red[cg + s][ul];
        __syncthreads();
    }
    if (cg == 0) {
        avec[b*TT + u] = red[0][ul];
        tmask[b*TT + u] = (u < text_len[b]) ? 1.f : 0.f;
    }
    if (tid < 128) {
        int t = uc*128 + tid;
        smask[b*TS + t] = (t < spec_len[b]) ? 1.f : 0.f;
    }
}

// ---------------------------------------------------------------------------
// gemm: nc[b][t][u] = avec[b][u] + sum_k X[k][t] * Bmat[k][u]
// X[2c][t] = z[b][c][t], X[2c+1][t] = -0.5*z^2.
// 128x256 tile, 512 threads, 8x8 microtile. Near the f32 FLOP floor (~82us).
// Per-output k-accumulation order is ascending k with one FMA each —
// bit-identical nc across rounds.
__global__ __launch_bounds__(512, 2) void vits_gemm(
    const float* __restrict__ z, const float* __restrict__ Bmat,
    const float* __restrict__ avec, float* __restrict__ out)
{
    const int b  = blockIdx.z;
    const int t0 = blockIdx.y * 128;
    const int u0 = blockIdx.x * 256;
    __shared__ float As[8][128];
    __shared__ float Bs[8][256];
    const int tid = threadIdx.x;
    const int tx = tid & 31, ty = tid >> 5;      // tx: u-group, ty: t-group
    float acc[8][8] = {};
    const float* zb = z    + (size_t)b * CC * TS;
    const float* Bb = Bmat + (size_t)b * KK * TT;

    const int c_l = tid >> 6;           // z channel (0..3 used, tid<256)
    const int t_l = (tid & 63) * 2;     // 0..126
    const int k_b = tid >> 6;           // 0..7 (B: 8 rows/panel)
    const int u_l = (tid & 63) * 4;     // 0..252

    float2 zr = make_float2(0.f, 0.f);
    if (tid < 256) zr = *(const float2*)(zb + (size_t)c_l*TS + t0 + t_l);
    float4 br = *(const float4*)(Bb + (size_t)k_b*TT + u0 + u_l);

    for (int kc = 0; kc < KK/8; ++kc) {
        if (tid < 256) {
            *(float2*)&As[2*c_l  ][t_l] = make_float2(zr.x, zr.y);
            *(float2*)&As[2*c_l+1][t_l] = make_float2(-0.5f*zr.x*zr.x, -0.5f*zr.y*zr.y);
        }
        *(float4*)&Bs[k_b][u_l] = br;
        __syncthreads();
        if (kc + 1 < KK/8) {            // prefetch next panel (overlaps compute)
            if (tid < 256)
                zr = *(const float2*)(zb + (size_t)((kc+1)*4 + c_l)*TS + t0 + t_l);
            br = *(const float4*)(Bb + (size_t)((kc+1)*8 + k_b)*TT + u0 + u_l);
        }
        #pragma unroll
        for (int k = 0; k < 8; ++k) {
            float4 a0 = *(const float4*)&As[k][ty*4];
            float4 a1 = *(const float4*)&As[k][ty*4 + 64];
            float4 b0 = *(const float4*)&Bs[k][tx*4];
            float4 b1 = *(const float4*)&Bs[k][tx*4 + 128];
            float aa[8] = {a0.x,a0.y,a0.z,a0.w,a1.x,a1.y,a1.z,a1.w};
            float bb[8] = {b0.x,b0.y,b0.z,b0.w,b1.x,b1.y,b1.z,b1.w};
            #pragma unroll
            for (int i = 0; i < 8; ++i)
                #pragma unroll
                for (int j = 0; j < 8; ++j)
                    acc[i][j] += aa[i]*bb[j];
        }
        __syncthreads();
    }

    float4 ab0 = *(const float4*)(avec + b*TT + u0 + tx*4);
    float4 ab1 = *(const float4*)(avec + b*TT + u0 + tx*4 + 128);
    float ab[8] = {ab0.x,ab0.y,ab0.z,ab0.w,ab1.x,ab1.y,ab1.z,ab1.w};
    #pragma unroll
    for (int i = 0; i < 8; ++i) {
        int tt = t0 + ((i < 4) ? (ty*4 + i) : (64 + ty*4 + (i-4)));
        float* orow = out + (size_t)((size_t)b*TS + tt)*TT + u0;
        float4 o0, o1;
        o0.x = acc[i][0] + ab[0]; o0.y = acc[i][1] + ab[1];
        o0.z = acc[i][2] + ab[2]; o0.w = acc[i][3] + ab[3];
        o1.x = acc[i][4] + ab[4]; o1.y = acc[i][5] + ab[5];
        o1.z = acc[i][6] + ab[6]; o1.w = acc[i][7] + ab[7];
        *(float4*)(orow + tx*4)       = o0;
        *(float4*)(orow + tx*4 + 128) = o1;
    }
}

// ---------------------------------------------------------------------------
// DPP full-wave rotate-by-1: lane n <- lane (n-1)&63 (wave_ror:1 = 0x13C).
__device__ __forceinline__ float dpp_ror1_f32(float v) {
    union { float f; int i; } u, r;
    u.f = v;
    r.i = __builtin_amdgcn_update_dpp(0, u.i, 0x13C, 0xF, 0xF, false);
    return r.f;
}

// ---------------------------------------------------------------------------
// dp: forward Viterbi (f32), SYSTOLIC wave-skewed tiling (R19-exact: ring 32
// with STATIC indices — R20's ring-64 used a runtime-c index -> scratch
// spill, WRITE_SIZE 192->2240KB, dp 221->417us. Rule #20.). 8 waves x 64
// auth columns, no ghost columns. Wave w runs chunk c (32 steps) only after
// wave w-1 completed chunk c (LDS prog[] + s_sleep spin). Boundary
// q[t-1][64w-1] flows via a 256-slot LDS ring; 6-chunk flow gate guards
// aliasing; waits acyclic.
// dirs bit-packed per col along t (32-t windows), bank-swizzled.
#define DIRS(j,w) dirs[((j)<<6) | ((w) ^ ((j) & 31))]

__global__ __launch_bounds__(512, 1) void vits_dp(
    const float* __restrict__ nc,
    const int* __restrict__ spec_len, const int* __restrict__ text_len,
    float* __restrict__ dur, float* __restrict__ logw, int* __restrict__ jt)
{
    __shared__ unsigned int dirs[TT*(TS/32)];   // 128 KB (swizzled)
    __shared__ float bq[8][256];                // 8 KB boundary rings
    __shared__ int prog[8];                     // completed chunks per wave
    __shared__ int Tr[TT + 1];                  // 2 KB

    const int tid  = threadIdx.x;
    const int lane = tid & 63;
    const int wid  = tid >> 6;                  // 0..7
    const int b = blockIdx.x;
    const int SL = spec_len[b], TL = text_len[b];
    const int col = (wid << 6) + lane;          // every lane is authoritative
    const bool l0  = (lane == 0);
    const bool l63 = (lane == 63);

    float q = (col == 0) ? 0.0f : NEGCF;
    unsigned int bits = 0;

    const float* ncb = nc + (size_t)b*TS*TT + col;
    float pf[32];
    #pragma unroll
    for (int i = 0; i < 32; ++i) pf[i] = ncb[(size_t)i*TT];
    const float* pcur = ncb + (size_t)32*TT;    // rows past SL read junk inside d_out; never consumed

    for (int i = tid; i < 8*256; i += 512) ((float*)bq)[i] = NEGCF;
    if (tid < 8) prog[tid] = 0;
    __syncthreads();

    volatile int* vprog = (volatile int*)prog;
    const int nch = SL >> 5;

    for (int c = 0; c < nch; ++c) {
        if (wid > 0) { while (vprog[wid-1] < c+1) __builtin_amdgcn_s_sleep(1); }
        if (wid < 7 && c > 6) { while (vprog[wid+1] < c-6) __builtin_amdgcn_s_sleep(1); }
        asm volatile("" ::: "memory");

        // boundary values for this chunk: slots (32c-4 .. 32c+31) & 255
        float4 R[9];
        R[0] = *(const float4*)&bq[wid][(c*32 + 252) & 255];
        #pragma unroll
        for (int g = 1; g < 9; ++g)
            R[g] = *(const float4*)&bq[wid][(c*32 + (g-1)*4) & 255];

        float4 wbuf;
        #pragma unroll
        for (int s = 0; s < 32; ++s) {
            float f = pf[s & 31];
            pf[s & 31] = *pcur;                  // prefetch row t+32 (static idx)
            pcur += TT;
            // boundary for step t=32c+s lives at slot 32c-1+s -> R[(s+3)/4][(s+3)%4]
            float B = ((const float*)&R[(s+3) >> 2])[(s+3) & 3];
            float qr = dpp_ror1_f32(q);
            float qprev = l0 ? B : qr;           // q[t-1][col-1]
            bool d = (qprev >= q);               // ref: q_shift >= q
            bits = (bits << 1) | (unsigned)d;
            q = f + fmaxf(qprev, q);
            ((float*)&wbuf)[s & 3] = q;          // static index (unrolled)
            if ((s & 3) == 3) {
                if (l63 && wid < 7)
                    *(float4*)&bq[wid+1][(c*32 + s - 3) & 255] = wbuf;
            }
        }
        DIRS(col, c) = bits;
        bits = 0;
        asm volatile("s_waitcnt lgkmcnt(0)" ::: "memory");
        if (l0) vprog[wid] = c + 1;
    }

    // tail (SL & 31 steps): fully serialized across waves (tiny)
    const int rem = SL & 31;
    if (rem) {
        if (wid > 0) { while (vprog[wid-1] < nch+1) __builtin_amdgcn_s_sleep(1); }
        asm volatile("" ::: "memory");
        for (int t = nch*32; t < SL; ++t) {
            float f = ncb[(size_t)t*TT];
            float B = *(volatile float*)&bq[wid][(t-1) & 255];
            float qr = dpp_ror1_f32(q);
            float qprev = l0 ? B : qr;
            bool d = (qprev >= q);
            bits = (bits << 1) | (unsigned)d;
            q = f + fmaxf(qprev, q);
            if (l63 && wid < 7) *(volatile float*)&bq[wid+1][t & 255] = q;
            asm volatile("s_waitcnt lgkmcnt(0)" ::: "memory");
        }
        DIRS(col, SL >> 5) = bits << (32 - rem);
        asm volatile("s_waitcnt lgkmcnt(0)" ::: "memory");
        if (l0) vprog[wid] = nch + 1;
    }
    __syncthreads();

    for (int i = tid; i <= TT; i += 512) Tr[i] = 0;
    __syncthreads();

    if (tid == 0) {
        Tr[TL] = SL;
        int j = TL - 1, tc = SL - 1;
        // Tr[j] = first frame aligned to text index j (transition time)
        while (j > 0 && tc >= 0) {
            int w = tc >> 5;
            int bcur = 31 - (tc & 31);
            unsigned int W = DIRS(j, w) & (0xFFFFFFFFu << bcur);
            if (W) {
                int bp = __ffs(W) - 1;          // lowest set bit >= bcur
                int tp = (w << 5) + 31 - bp;    // = largest t' <= tc with d=1
                Tr[j] = tp;
                --j;
                tc = tp - 1;
            } else {
                if (w == 0) break;
                tc = (w << 5) - 1;
            }
        }
    }
    __syncthreads();

    for (int u = tid; u < TT; u += 512) {
        float dv = (u < TL) ? (float)(Tr[u+1] - Tr[u]) : 0.0f;
        dur[b*TT + u] = dv;
        logw[b*TT + u] = (u < TL) ? logf(dv + 1e-6f) : 0.0f;
    }
    // jt: range-fill [Tr[u], Tr[u+1]) -> u
    for (int u = 0; u < TL; ++u) {
        int t1 = Tr[u+1];
        for (int t = Tr[u] + tid; t < t1; t += 512) jt[b*TS + t] = u;
    }
    for (int t = SL + tid; t < TS; t += 512) jt[b*TS + t] = -1;
}

// ---------------------------------------------------------------------------
// fused output pass: blocks [0, PB) write path (one-hot rows), blocks
// [PB, PB+MB) write mexp/lexp gathers. One launch, shared BW.
#define PB 1024
#define MB 2048
__global__ void vits_out(const int* __restrict__ jt,
    const float* __restrict__ m_p, const float* __restrict__ logs_p,
    float4* __restrict__ path, float4* __restrict__ mexp, float4* __restrict__ lexp)
{
    if (blockIdx.x < PB) {
        int idx = blockIdx.x*blockDim.x + threadIdx.x;
        const int total = BB*TS*(TT/4);
        for (; idx < total; idx += PB*blockDim.x) {
            int u4 = idx & (TT/4 - 1);
            int bt = idx >> 7;
            int j = jt[bt];
            float4 v = make_float4(0.f,0.f,0.f,0.f);
            int r = j - (u4 << 2);
            if (r >= 0 && r < 4) ((float*)&v)[r] = 1.f;
            path[idx] = v;
        }
    } else {
        int idx = (blockIdx.x - PB)*blockDim.x + threadIdx.x;
        const int total = BB*CC*(TS/4);
        for (; idx < total; idx += MB*blockDim.x) {
            int t4 = idx & (TS/4 - 1);
            int bc = idx >> 9;
            int b = bc / CC;
            int4 jv = *(const int4*)(jt + b*TS + (t4 << 2));
            const float* mrow = m_p    + (size_t)bc*TT;
            const float* lrow = logs_p + (size_t)bc*TT;
            float4 mv, lv;
            mv.x = (jv.x >= 0) ? mrow[jv.x] : 0.f;  lv.x = (jv.x >= 0) ? lrow[jv.x] : 0.f;
            mv.y = (jv.y >= 0) ? mrow[jv.y] : 0.f;  lv.y = (jv.y >= 0) ? lrow[jv.y] : 0.f;
            mv.z = (jv.z >= 0) ? mrow[jv.z] : 0.f;  lv.z = (jv.z >= 0) ? lrow[jv.z] : 0.f;
            mv.w = (jv.w >= 0) ? mrow[jv.w] : 0.f;  lv.w = (jv.w >= 0) ? lrow[jv.w] : 0.f;
            mexp[idx] = mv;
            lexp[idx] = lv;
        }
    }
}

// ---------------------------------------------------------------------------
extern "C" void kernel_launch(void* const* d_in, const int* in_sizes, int n_in,
                              void* d_out, int out_size, void* d_ws, size_t ws_size,
                              hipStream_t stream) {
    const float* z_p      = (const float*)d_in[0];
    const float* m_p      = (const float*)d_in[1];
    const float* logs_p   = (const float*)d_in[2];
    const int*   spec_len = (const int*)d_in[3];
    const int*   text_len = (const int*)d_in[4];
    float* out = (float*)d_out;

    float* Bmat = (float*)d_ws;                  // [B][384][512] f32 = 12.6 MB
    float* avec = Bmat + (size_t)BB*KK*TT;       // [B][512]
    int*   jt   = (int*)(avec + BB*TT);          // [B][2048]

    float* path  = out + OFF_PATH;   // doubles as neg_cent staging
    float* dur   = out + OFF_DUR;
    float* logw  = out + OFF_LOGW;
    float* mexp  = out + OFF_MEXP;
    float* lexp  = out + OFF_LEXP;
    float* tmask = out + OFF_TMASK;
    float* smask = out + OFF_SMASK;

    vits_prep<<<dim3(16, BB), 512, 0, stream>>>(m_p, logs_p, spec_len, text_len,
                                                Bmat, avec, tmask, smask);
    vits_gemm<<<dim3(TT/256, TS/128, BB), 512, 0, stream>>>(z_p, Bmat, avec, path);
    vits_dp<<<BB, 512, 0, stream>>>(path, spec_len, text_len, dur, logw, jt);
    vits_out<<<PB + MB, 256, 0, stream>>>(jt, m_p, logs_p,
                                          (float4*)path, (float4*)mexp, (float4*)lexp);
}